// Round 11
// baseline (59.783 us; speedup 1.0000x reference)
//
#include <hip/hip_runtime.h>

typedef __attribute__((ext_vector_type(8))) short short8;
typedef __attribute__((ext_vector_type(4))) short short4v;
typedef __attribute__((ext_vector_type(4))) float f32x4;

#define MFMA_16x16x32_BF16(A, B, C) __builtin_amdgcn_mfma_f32_16x16x32_bf16(A, B, C, 0, 0, 0)

// float -> bf16 bits, round-to-nearest-even (inputs always finite here)
__device__ __forceinline__ unsigned short f2bf(float x) {
    unsigned int u = __builtin_bit_cast(unsigned int, x);
    u = (u + 0x7FFFu + ((u >> 16) & 1u)) >> 16;
    return (unsigned short)u;
}

// ---------------------------------------------------------------------------
// Kernel 1: pack Wk|Wq|Wv (fp32 [1024][64]) -> Wt bf16 [192][1024] transposed,
// with the proj LDS bank-swizzle PRE-BAKED: within each 64-k tile, 8-short
// chunk c holds logical chunk c ^ (n&7).  (G21: global_load_lds writes LDS
// linearly, so the conflict-free permutation must come from the source.)
// ---------------------------------------------------------------------------
__global__ __launch_bounds__(256) void wconv_kernel(const float* __restrict__ Wk,
                                                    const float* __restrict__ Wq,
                                                    const float* __restrict__ Wv,
                                                    unsigned short* __restrict__ Wt) {
    const int n = blockIdx.x;                       // 0..191
    const float* W = (n < 64) ? Wk : (n < 128) ? Wq : Wv;
    const int col = n & 63;
    const int sw = (n & 7) << 3;
    for (int k = threadIdx.x; k < 1024; k += 256) {
        const int kd = (k & ~56) | ((k ^ sw) & 56);   // XOR chunk bits 3..5
        Wt[(size_t)n * 1024 + kd] = f2bf(W[(size_t)k * 64 + col]);
    }
}

// ---------------------------------------------------------------------------
// Kernel 2: QKV projection GEMM — BM=64 (the L2-ratio fix: W-L2 traffic per
// CU-iter = blocks/CU * BN*BK*2B; W:X = BN/(2*BM) = 1.5x here vs 3x at BM=32,
// which capped every prior variant at ~3x the X streaming floor).
// BM=64, BN=192, BK=64; 512 thr = 8 waves as 2 row-groups x 4 col-groups
// (wave = 32 rows x 48 cols: per k-sub 2 A + 3 W ds_reads -> 6 MFMAs, 0.83
// reads/MFMA vs 1.33 before).  Grid 256 = 1 block/CU.
// Same proven 2-phase glds + counted-vmcnt pipeline (vmcnt(2): the 2 A
// prefetch loads stay in flight across the barrier).
// ---------------------------------------------------------------------------
__global__ __launch_bounds__(512, 2) void proj_kernel(const float* __restrict__ X,
                                                      const unsigned short* __restrict__ Wt,
                                                      unsigned short* __restrict__ Kb,
                                                      unsigned short* __restrict__ Qb,
                                                      unsigned short* __restrict__ Vtg) {
    __shared__ __attribute__((aligned(16))) unsigned short Wl[2][192 * 64];  // glds dbuf 48KB
    __shared__ __attribute__((aligned(16))) unsigned short Al[2][64 * 72];   // pad 64->72, 18.4KB
    const int t = threadIdx.x;
    const int w = t >> 6, lane = t & 63, lr = lane & 15, g = lane >> 4;
    const int rw = w >> 2, cw = w & 3;
    const int r0 = blockIdx.x * 64;

    f32x4 acc[2][3] = {};

    // A staging coords: row = t>>3 (0..63), chunk j = t&7 (8 floats = 32B/thr)
    const int ar = t >> 3, aj = t & 7;
    const float* xsrc = X + (size_t)(r0 + ar) * 1024 + aj * 8;

    // ---- prologue: stage A(0) synchronously ----
    {
        float4 a0 = *(const float4*)xsrc;
        float4 a1 = *(const float4*)(xsrc + 4);
        uint4 aw;
        aw.x = (unsigned)f2bf(a0.x) | ((unsigned)f2bf(a0.y) << 16);
        aw.y = (unsigned)f2bf(a0.z) | ((unsigned)f2bf(a0.w) << 16);
        aw.z = (unsigned)f2bf(a1.x) | ((unsigned)f2bf(a1.y) << 16);
        aw.w = (unsigned)f2bf(a1.z) | ((unsigned)f2bf(a1.w) << 16);
        *(uint4*)&Al[0][ar * 72 + aj * 8] = aw;
    }
#pragma unroll
    for (int i = 0; i < 3; ++i) {                          // W(0) -> Wl[0]
        const int q = t + 512 * i;
        const unsigned short* src = Wt + (size_t)(q >> 3) * 1024 + (q & 7) * 8;
        __builtin_amdgcn_global_load_lds((const __attribute__((address_space(1))) void*)src,
                                         (__attribute__((address_space(3))) void*)&Wl[0][q * 8],
                                         16, 0, 0);
    }
    __builtin_amdgcn_sched_barrier(0);                     // glds older than A-issue
    float4 fly0 = *(const float4*)(xsrc + 64);             // A(1) flies across barrier
    float4 fly1 = *(const float4*)(xsrc + 68);
    asm volatile("s_waitcnt vmcnt(2) lgkmcnt(0)" ::: "memory");
    __builtin_amdgcn_s_barrier();                          // tiles t=0 ready

    for (int t16 = 0; t16 < 16; ++t16) {
        const int cur = t16 & 1;
        if (t16 < 15) {
            // convert A(t+1): auto-wait drains the 2 fly loads only
            uint4 aw;
            aw.x = (unsigned)f2bf(fly0.x) | ((unsigned)f2bf(fly0.y) << 16);
            aw.y = (unsigned)f2bf(fly0.z) | ((unsigned)f2bf(fly0.w) << 16);
            aw.z = (unsigned)f2bf(fly1.x) | ((unsigned)f2bf(fly1.y) << 16);
            aw.w = (unsigned)f2bf(fly1.z) | ((unsigned)f2bf(fly1.w) << 16);
            *(uint4*)&Al[cur ^ 1][ar * 72 + aj * 8] = aw;
            const int k1 = (t16 + 1) * 64;
#pragma unroll
            for (int i = 0; i < 3; ++i) {                  // glds W(t+1)
                const int q = t + 512 * i;
                const unsigned short* src = Wt + (size_t)(q >> 3) * 1024 + k1 + (q & 7) * 8;
                __builtin_amdgcn_global_load_lds((const __attribute__((address_space(1))) void*)src,
                                                 (__attribute__((address_space(3))) void*)&Wl[cur ^ 1][q * 8],
                                                 16, 0, 0);
            }
            __builtin_amdgcn_sched_barrier(0);             // pin: glds older than A-issue
            const int anext = (t16 + 2 < 15) ? (t16 + 2) : 15;   // clamp keeps count invariant
            fly0 = *(const float4*)(xsrc + anext * 64);
            fly1 = *(const float4*)(xsrc + anext * 64 + 4);
        }

        // ---- compute tile t from buf cur ----
        short8 af[2][2];                                   // [row-group t_][k-sub]
#pragma unroll
        for (int t_ = 0; t_ < 2; ++t_)
#pragma unroll
            for (int sub = 0; sub < 2; ++sub)
                af[t_][sub] = *(const short8*)&Al[cur][(32 * rw + 16 * t_ + lr) * 72 + 32 * sub + 8 * g];
#pragma unroll
        for (int c = 0; c < 3; ++c) {
            const int row = 48 * cw + 16 * c + lr;
#pragma unroll
            for (int sub = 0; sub < 2; ++sub) {
                const int cs = (4 * sub + g) ^ (lr & 7);   // un-swizzle
                short8 wf = *(const short8*)&Wl[cur][row * 64 + cs * 8];
                acc[0][c] = MFMA_16x16x32_BF16(af[0][sub], wf, acc[0][c]);
                acc[1][c] = MFMA_16x16x32_BF16(af[1][sub], wf, acc[1][c]);
            }
        }
        if (t16 < 15) {
            // counted-vmcnt barrier: glds drained, 2 A-prefetch loads stay live
            asm volatile("s_waitcnt vmcnt(2) lgkmcnt(0)" ::: "memory");
            __builtin_amdgcn_s_barrier();
        }
    }

    // ---- epilogue: C/D layout col = lane&15 (W-col), row = 4*(lane>>4)+reg ----
    const int bb = r0 >> 11;                      // batch (r0 multiple of 64 -> no straddle)
#pragma unroll
    for (int t_ = 0; t_ < 2; ++t_) {
        const int row = r0 + 32 * rw + 16 * t_ + 4 * g;
        const int sb0 = (r0 & 2047) + 32 * rw + 16 * t_ + 4 * g;
#pragma unroll
        for (int i = 0; i < 3; ++i) {
            const int cg = cw * 3 + i;            // global col-tile 0..11
            if (cg < 4) {
#pragma unroll
                for (int r = 0; r < 4; ++r)
                    Kb[(size_t)(row + r) * 64 + 16 * cg + lr] = f2bf(acc[t_][i][r]);
            } else if (cg < 8) {
#pragma unroll
                for (int r = 0; r < 4; ++r)
                    Qb[(size_t)(row + r) * 64 + 16 * (cg - 4) + lr] = f2bf(acc[t_][i][r]);
            } else {
                const int h = 16 * (cg - 8) + lr;
                uint2 e;
                e.x = (unsigned)f2bf(acc[t_][i][0]) | ((unsigned)f2bf(acc[t_][i][1]) << 16);
                e.y = (unsigned)f2bf(acc[t_][i][2]) | ((unsigned)f2bf(acc[t_][i][3]) << 16);
                *(uint2*)(Vtg + (size_t)bb * 64 * 2048 + (size_t)h * 2048 + sb0) = e;
            }
        }
    }
}

// ---------------------------------------------------------------------------
// Kernel 3: causal flash attention, band-pair blocks, 8 waves, PING-PONG
// K/V prefetch (named sets, no copies — the r3 idea minus its mistake).
// Block = bands {63-p (hi), p (lo)} of 32 q-rows each -> exactly 65 kv-steps.
// 8 waves split the 65 steps contiguously; hi-band results are flushed to
// LDS before the lo loop (frees registers for the double K/V set).
// K and V^T fragments load DIRECTLY from global (L2-resident); prefetch of
// step s+1 is pinned above compute of step s with sched_barrier(0).
// ---------------------------------------------------------------------------
__global__ __launch_bounds__(512, 2) void attn_kernel(const unsigned short* __restrict__ Kb,
                                                      const unsigned short* __restrict__ Qb,
                                                      const unsigned short* __restrict__ Vtg,
                                                      float* __restrict__ out) {
    __shared__ __attribute__((aligned(16))) float Pacc[16][32][68];  // [slot][q][h] pad 68
    __shared__ float Pml[2][16][32];                                 // m / l per slot,q

    const int t = threadIdx.x;
    const int w = t >> 6, lane = t & 63;
    const int lr = lane & 15, g = lane >> 4;
    const int p = blockIdx.x, b = blockIdx.y;
    const int nhi = 64 - p;                      // steps for hi band
    const int q0h = (63 - p) * 32, q0l = p * 32;
    const size_t rowbase = (size_t)b * 2048;
    const size_t vbase = (size_t)b * 64 * 2048;
    const float NEG_INF = -__builtin_inff();
    const float SCALE2 = 0.03125f * 1.4426950408889634f;   // d^-0.5 * log2(e)

    const int s0 = (w * 65) >> 3, s1 = ((w + 1) * 65) >> 3;

    auto loadKV = [&](int kv0, short8 (&kf)[2][2], short8 (&vf)[4]) {
#pragma unroll
        for (int f = 0; f < 2; ++f)
#pragma unroll
            for (int hh = 0; hh < 2; ++hh)
                kf[f][hh] = *(const short8*)(Kb + (rowbase + kv0 + 16 * f + lr) * 64 + 32 * hh + 8 * g);
#pragma unroll
        for (int fh = 0; fh < 4; ++fh) {
            const unsigned short* vp = Vtg + vbase + (size_t)(16 * fh + lr) * 2048 + kv0 + 4 * g;
            short4v v0 = *(const short4v*)vp;
            short4v v1 = *(const short4v*)(vp + 16);
            short8 vv;
            vv[0] = v0[0]; vv[1] = v0[1]; vv[2] = v0[2]; vv[3] = v0[3];
            vv[4] = v1[0]; vv[5] = v1[1]; vv[6] = v1[2]; vv[7] = v1[3];
            vf[fh] = vv;
        }
    };

    auto stepc = [&](int kv0, int q0, const short8 (&qf)[2][2],
                     const short8 (&kf)[2][2], const short8 (&vf)[4],
                     f32x4 (&acc)[2][4], float (&m2)[2], float (&ls)[2]) {
#pragma unroll
        for (int sub = 0; sub < 2; ++sub) {
            f32x4 sv[2];
#pragma unroll
            for (int f = 0; f < 2; ++f) {
                f32x4 x = {};
                x = MFMA_16x16x32_BF16(kf[f][0], qf[sub][0], x);
                x = MFMA_16x16x32_BF16(kf[f][1], qf[sub][1], x);
                sv[f] = x;
            }
            const int q = q0 + 16 * sub + lr;
            float pvv[8], tmax = NEG_INF;
#pragma unroll
            for (int f = 0; f < 2; ++f)
#pragma unroll
                for (int r = 0; r < 4; ++r) {
                    int kp = kv0 + 16 * f + 4 * g + r;
                    float sc = sv[f][r] * SCALE2;
                    sc = (kp <= q) ? sc : NEG_INF;
                    pvv[4 * f + r] = sc;
                    tmax = fmaxf(tmax, sc);
                }
            tmax = fmaxf(tmax, __shfl_xor(tmax, 16));
            tmax = fmaxf(tmax, __shfl_xor(tmax, 32));
            float mnew = fmaxf(m2[sub], tmax);     // finite: kv0 <= q0 <= q always
            float alpha = exp2f(m2[sub] - mnew);
            float psum = 0.f;
            short8 pf;
#pragma unroll
            for (int e = 0; e < 8; ++e) {
                float pe = exp2f(pvv[e] - mnew);
                psum += pe;
                pf[e] = (short)f2bf(pe);
            }
            psum += __shfl_xor(psum, 16);
            psum += __shfl_xor(psum, 32);
            ls[sub] = ls[sub] * alpha + psum;
            m2[sub] = mnew;
#pragma unroll
            for (int fh = 0; fh < 4; ++fh) {
                acc[sub][fh][0] *= alpha; acc[sub][fh][1] *= alpha;
                acc[sub][fh][2] *= alpha; acc[sub][fh][3] *= alpha;
                acc[sub][fh] = MFMA_16x16x32_BF16(vf[fh], pf, acc[sub][fh]);
            }
        }
    };

    // ping-pong band runner: prefetch step s+1 (named set) above compute of s
    auto runband = [&](int sBeg, int sEnd, int base, int q0, const short8 (&qf)[2][2],
                       f32x4 (&acc)[2][4], float (&m2)[2], float (&ls)[2]) {
        int s = sBeg;
        if (s >= sEnd) return;
        short8 kfA[2][2], vfA[4], kfB[2][2], vfB[4];
        loadKV((s - base) * 32, kfA, vfA);
        __builtin_amdgcn_sched_barrier(0);
        while (true) {
            if (s + 1 < sEnd) {
                loadKV((s + 1 - base) * 32, kfB, vfB);
                __builtin_amdgcn_sched_barrier(0);
            }
            stepc((s - base) * 32, q0, qf, kfA, vfA, acc, m2, ls);
            ++s; if (s >= sEnd) break;
            if (s + 1 < sEnd) {
                loadKV((s + 1 - base) * 32, kfA, vfA);
                __builtin_amdgcn_sched_barrier(0);
            }
            stepc((s - base) * 32, q0, qf, kfB, vfB, acc, m2, ls);
            ++s; if (s >= sEnd) break;
        }
    };

    // ---- hi band ----
    {
        short8 qfH[2][2];
#pragma unroll
        for (int sub = 0; sub < 2; ++sub)
#pragma unroll
            for (int hh = 0; hh < 2; ++hh)
                qfH[sub][hh] = *(const short8*)(Qb + (rowbase + q0h + 16 * sub + lr) * 64 + 32 * hh + 8 * g);
        f32x4 accH[2][4] = {};
        float mH[2] = {NEG_INF, NEG_INF}, lH[2] = {0.f, 0.f};
        const int e = (s1 < nhi) ? s1 : nhi;
        runband(s0, e, 0, q0h, qfH, accH, mH, lH);
        // flush to slot w (frees the registers before the lo loop)
#pragma unroll
        for (int sub = 0; sub < 2; ++sub) {
#pragma unroll
            for (int fh = 0; fh < 4; ++fh)
                *(f32x4*)&Pacc[w][16 * sub + lr][16 * fh + 4 * g] = accH[sub][fh];
            if (g == 0) {
                Pml[0][w][16 * sub + lr] = mH[sub];
                Pml[1][w][16 * sub + lr] = lH[sub];
            }
        }
    }
    // ---- lo band ----
    {
        short8 qfL[2][2];
#pragma unroll
        for (int sub = 0; sub < 2; ++sub)
#pragma unroll
            for (int hh = 0; hh < 2; ++hh)
                qfL[sub][hh] = *(const short8*)(Qb + (rowbase + q0l + 16 * sub + lr) * 64 + 32 * hh + 8 * g);
        f32x4 accL[2][4] = {};
        float mL[2] = {NEG_INF, NEG_INF}, lL[2] = {0.f, 0.f};
        const int sBeg = (s0 > nhi) ? s0 : nhi;
        runband(sBeg, s1, nhi, q0l, qfL, accL, mL, lL);
#pragma unroll
        for (int sub = 0; sub < 2; ++sub) {
#pragma unroll
            for (int fh = 0; fh < 4; ++fh)
                *(f32x4*)&Pacc[8 + w][16 * sub + lr][16 * fh + 4 * g] = accL[sub][fh];
            if (g == 0) {
                Pml[0][8 + w][16 * sub + lr] = mL[sub];
                Pml[1][8 + w][16 * sub + lr] = lL[sub];
            }
        }
    }
    __syncthreads();

    // ---- combine: 512 thr -> 2 bands x 32 q x 8 h-groups ----
    {
        const int tb = t >> 8, t2 = t & 255;
        const int qq = t2 & 31, hb = (t2 >> 5) * 8;
        float mw[8], M = NEG_INF;
#pragma unroll
        for (int wv = 0; wv < 8; ++wv) {
            mw[wv] = Pml[0][tb * 8 + wv][qq];
            M = fmaxf(M, mw[wv]);
        }
        float wgt[8], L = 0.f;
#pragma unroll
        for (int wv = 0; wv < 8; ++wv) {
            wgt[wv] = exp2f(mw[wv] - M);           // exp2(-inf)=0 for idle waves
            L += wgt[wv] * Pml[1][tb * 8 + wv][qq];
        }
        f32x4 o0 = {}, o1 = {};
#pragma unroll
        for (int wv = 0; wv < 8; ++wv) {
            f32x4 a0 = *(const f32x4*)&Pacc[tb * 8 + wv][qq][hb];
            f32x4 a1 = *(const f32x4*)&Pacc[tb * 8 + wv][qq][hb + 4];
            o0 += wgt[wv] * a0;
            o1 += wgt[wv] * a1;
        }
        const float invL = 1.f / L;
        o0 *= invL; o1 *= invL;
        const int q0 = tb ? q0l : q0h;
        float* op = out + (rowbase + q0 + qq) * 64 + hb;
        *(f32x4*)op = o0;
        *(f32x4*)(op + 4) = o1;
    }
}

// ---------------------------------------------------------------------------
extern "C" void kernel_launch(void* const* d_in, const int* in_sizes, int n_in,
                              void* d_out, int out_size, void* d_ws, size_t ws_size,
                              hipStream_t stream) {
    const float* X  = (const float*)d_in[0];
    const float* Wk = (const float*)d_in[1];
    const float* Wq = (const float*)d_in[2];
    const float* Wv = (const float*)d_in[3];

    unsigned short* Wt  = (unsigned short*)d_ws;       // 192*1024 bf16 (swizzled)
    unsigned short* Kb  = Wt + 192 * 1024;             // [16384][64] bf16
    unsigned short* Qb  = Kb + 16384 * 64;             // [16384][64] bf16
    unsigned short* Vtg = Qb + 16384 * 64;             // [8][64][2048] bf16 (V^T)
    float* out = (float*)d_out;

    wconv_kernel<<<dim3(192), dim3(256), 0, stream>>>(Wk, Wq, Wv, Wt);
    proj_kernel<<<dim3(256), dim3(512), 0, stream>>>(X, Wt, Kb, Qb, Vtg);
    attn_kernel<<<dim3(32, 8), dim3(512), 0, stream>>>(Kb, Qb, Vtg, out);
}